// Round 10
// baseline (89.680 us; speedup 1.0000x reference)
//
#include <hip/hip_runtime.h>
#include <hip/hip_bf16.h>

// Strip-gather: one block per (x-tile, 128-px y-strip, batch) = 16x2x32 =
// 1024 blocks -> whole grid co-resident (4 blocks/CU). Amortizes the
// per-block fixed path (brush-table load, ballot, ramp) over 8 tiles.
// out[b,c,h,w] = (1/64) Σ_n Σ_p wy[h,p] Σ_q wx[w,q] patch[b,n,c,p,q]
// sigma=0.2 -> support radius 2 px => brush window <=20x20 px.
//
// Per block: wave-private brush table (64 float2 in registers); wave 0 builds
// a compacted job list (t<<6|n), tile-major, via 8 ballots + lane rank
// (expected ~9 jobs, worst case 192: a brush spans <=3 tiles). Main loop:
// one-ahead patch prefetch from the known job stream; invZ inline per wave
// (in the shadow of in-flight loads); stage1 T4[wi][p] via intra-wave
// branchless shuffles (ds_bpermute from exec-masked lanes is undefined ->
// weight-mask instead); ONE barrier; stage2 5 p-taps per pixel. Tiles flush
// (3 coalesced stores) as the job stream passes them; empty tiles get zeros.
// T4 double-buffered: reads of job j (buf j&1, before barrier j+1) vs writes
// of job j+2 (same buf, after barrier j+1) are separated by barrier j+1.
// Incremental Gaussian: w_{j+1}=w_j*u, u*=exp(-25); d0 clamped to [-3,3]
// keeps the chain finite for weight-masked lanes (0*finite==0).

#define E25 1.3887944e-11f   // exp(-25)

__global__ __launch_bounds__(256) void brush_strip(
        const float* __restrict__ brushes,   // [32,64,2]
        const float* __restrict__ patches,   // [32,64,3,16,16]
        float* __restrict__ out)             // [32,3,256,256]
{
    const int b    = blockIdx.z;
    const int tx   = blockIdx.x << 4;
    const int ty0  = blockIdx.y << 7;        // strip base: 8 tiles of 16 px
    const int tid  = threadIdx.x;
    const int lane = tid & 63;
    const int qi   = tid & 15;   // q (source) / wi (stage1) / w-col (stage2)
    const int pi   = tid >> 4;   // p (source) / h-row (stage2)
    const int w    = tx + qi;

    __shared__ float4 T4[2 * 16 * 21];       // [buf][wi][p(16)+pad5], c-packed
    __shared__ int    jobs[192];             // (t<<6)|n, tile-major
    __shared__ int    njobs;

    // zero p>=16 pads of both buffers once (stage1 writes only p<16);
    // the first job's barrier orders these vs the first stage2 reads
    if (tid < 160) {
        const int buf = tid / 80, r = tid % 80;
        T4[buf * 336 + (r / 5) * 21 + 16 + (r % 5)] = make_float4(0, 0, 0, 0);
    }

    // wave-private brush table
    const float2 g0 = ((const float2*)brushes)[(b << 6) + lane];
    const float bx = g0.x * 256.0f, by = g0.y * 256.0f;

    // wave 0: compacted tile-major job list via ballot + rank
    if (tid < 64) {
        int base = 0;
        const bool hx = (bx >= (float)tx - 9.5f) & (bx <= (float)tx + 24.5f);
#pragma unroll
        for (int t = 0; t < 8; ++t) {
            const float tyf = (float)(ty0 + (t << 4));
            const bool hit = hx & (by >= tyf - 9.5f) & (by <= tyf + 24.5f);
            const unsigned long long m = __ballot(hit);
            const int rank = __popcll(m & ((1ull << lane) - 1ull));
            if (hit) jobs[base + rank] = (t << 6) | lane;
            base += __popcll(m);             // uniform across lanes
        }
        if (tid == 0) njobs = base;
    }
    __syncthreads();

    const int cnt = njobs;
    float acc0 = 0.0f, acc1 = 0.0f, acc2 = 0.0f;
    int cur = 0;                             // next tile to flush
    const float sc = 1.0f / 64.0f;
    float* const obase = out + (((size_t)(b * 3)) << 16) + tx + qi;

    int job = 0;
    float r0, r1, r2;
    if (cnt > 0) {                           // uniform
        job = jobs[0];
        const float* wp = patches + (size_t)((b << 6) + (job & 63)) * 768;
        r0 = wp[tid]; r1 = wp[tid + 256]; r2 = wp[tid + 512];
    }

    for (int j = 0; j < cnt; ++j) {
        // one-ahead prefetch (uniform branch)
        int njob = -1; float n0, n1, n2;
        if (j + 1 < cnt) {
            njob = jobs[j + 1];
            const float* wq = patches + (size_t)((b << 6) + (njob & 63)) * 768;
            n0 = wq[tid]; n1 = wq[tid + 256]; n2 = wq[tid + 512];
        }

        const int t = job >> 6, n = job & 63;

        // flush tiles the stream has passed (uniform)
        while (cur < t) {
            float* ob = obase + ((ty0 + (cur << 4) + pi) << 8);
            ob[0] = acc0 * sc; ob[1 << 16] = acc1 * sc; ob[2 << 16] = acc2 * sc;
            acc0 = acc1 = acc2 = 0.0f;
            ++cur;
        }

        const float gx = __shfl(bx, n, 64);  // uniform n -> readlane
        const float gy = __shfl(by, n, 64);

        // normalizers, redundant per wave: lane k&31 -> axis k>>4, tap k&15
        float invz;
        {
            const int k = lane & 31;
            const float g  = (k >> 4) ? gy : gx;
            const float mu = g + (float)(k & 15) - 7.5f;
            const float fl = floorf(mu);
            float Z = 0.0f;
#pragma unroll
            for (int d = -1; d <= 2; ++d) {
                const float c = fl + (float)d;
                if (c >= -8.0f && c <= 263.0f) {   // padded coord range
                    const float u = c - mu;
                    Z += __expf(-12.5f * u * u);
                }
            }
            invz = 1.0f / (Z + 1e-7f);
        }
        const float zx  = __shfl(invz, qi, 64);        // invZx[qi]
        const float zyp = __shfl(invz, 16 + pi, 64);   // invZy[pi]
        const float v0 = r0 * zx, v1 = r1 * zx, v2 = r2 * zx;

        const int buf = (j & 1) * 336;

        // ---- stage1: T4[wi=qi][p=pi], branchless intra-wave shuffles ----
        {
            const float ax  = (float)w - gx + 7.5f;
            const bool  okx = (ax >= -2.5f) & (ax <= 17.5f);
            int qlo = (int)ceilf(ax - 2.0f);
            qlo = qlo < 0 ? 0 : (qlo > 15 ? 15 : qlo);
            float d0 = ax - (float)qlo;
            d0 = fminf(fmaxf(d0, -3.0f), 3.0f);   // keep exp chain finite
            float wgt = okx ? __expf(-12.5f * d0 * d0) : 0.0f;
            float u   = __expf(25.0f * d0 - 12.5f);
            const int base = ((pi & 3) << 4) + qlo;    // intra-wave src lane
            float4 s = make_float4(0, 0, 0, 0);
#pragma unroll
            for (int jj = 0; jj < 5; ++jj) {
                const float t0 = __shfl(v0, base + jj, 64);  // all lanes active
                const float t1 = __shfl(v1, base + jj, 64);
                const float t2 = __shfl(v2, base + jj, 64);
                const float wj = (qlo + jj < 16) ? wgt : 0.0f;
                s.x += wj * t0; s.y += wj * t1; s.z += wj * t2;
                wgt *= u; u *= E25;
            }
            s.x *= zyp; s.y *= zyp; s.z *= zyp;
            T4[buf + qi * 21 + pi] = s;
        }
        __syncthreads();                     // the one barrier per job

        // ---- stage2: 5 p-taps from T4 (pads exact zeros) ----------------
        {
            const float ay = (float)(ty0 + (t << 4) + pi) - gy + 7.5f;
            if (ay >= -2.5f && ay <= 17.5f) {   // divergent ok: LDS only
                int plo = (int)ceilf(ay - 2.0f);
                plo = plo < 0 ? 0 : (plo > 15 ? 15 : plo);
                const float d0 = ay - (float)plo;    // in [-2.5, 2.5]
                float wgt = __expf(-12.5f * d0 * d0);
                float u   = __expf(25.0f * d0 - 12.5f);
                const float4* row = &T4[buf + qi * 21 + plo];
#pragma unroll
                for (int jj = 0; jj < 5; ++jj) {
                    const float4 v = row[jj];
                    acc0 += wgt * v.x; acc1 += wgt * v.y; acc2 += wgt * v.z;
                    wgt *= u; u *= E25;
                }
            }
        }

        job = njob; r0 = n0; r1 = n1; r2 = n2;
    }

    // flush remaining tiles (zeros for empty ones)
    while (cur < 8) {
        float* ob = obase + ((ty0 + (cur << 4) + pi) << 8);
        ob[0] = acc0 * sc; ob[1 << 16] = acc1 * sc; ob[2 << 16] = acc2 * sc;
        acc0 = acc1 = acc2 = 0.0f;
        ++cur;
    }
}

extern "C" void kernel_launch(void* const* d_in, const int* in_sizes, int n_in,
                              void* d_out, int out_size, void* d_ws, size_t ws_size,
                              hipStream_t stream) {
    const float* brushes = (const float*)d_in[0];
    const float* patches = (const float*)d_in[1];
    float* out = (float*)d_out;
    brush_strip<<<dim3(16, 2, 32), dim3(256), 0, stream>>>(brushes, patches, out);
}

// Round 11
// 81.757 us; speedup vs baseline: 1.0969x; 1.0969x over previous
//
#include <hip/hip_runtime.h>
#include <hip/hip_bf16.h>

// One-wave-per-tile gather: 16x16 tile per 64-thread block (8192 blocks).
// out[b,c,h,w] = (1/64) Σ_n Σ_p wy[h,p] Σ_q wx[w,q] patch[b,n,c,p,q]
// sigma=0.2 -> support radius 2 px => brush window <=20x20 px.
//
// Lane l = (qi = l&15, pi = l>>4, pi in 0..3). Lane holds patch[c][pi+4k][qi]
// for k=0..3 (12 regs, coalesced loads: addr = c*256 + k*64 + l). So
// patch[c][p][q] lives in lane ((p&3)<<4)|q, reg slot p>>2 — for stage1
// entry (wi=qi, p=pi+4k) the source lane is (pi<<4)+qlo+j and the slot is k:
// both loop-uniform => plain ds_bpermute per (j,k,c).
// Stage1: 4 T-entries/lane -> T4[wi][p] in LDS (x-contraction, shared by the
// tile's 16 columns); one near-free 1-wave __syncthreads; stage2: 4 px/lane,
// 5 p-taps each from T4. All waves fully independent — no cross-wave
// barrier coupling (R7's 4-wave lockstep was the stall source).
// Shuffles run branchless (ds_bpermute from exec-masked lanes is undefined);
// out-of-range taps are weight-masked; d0 clamped to [-3,3] keeps the
// incremental exp chain finite (w_{j+1}=w_j*u, u*=exp(-25); 0*finite==0).
// T4 pads p=16..20 zeroed once (plo<=15, j<=4 => p<=19 reads exact zeros).
// Same-wave T4 WAR/RAW across brushes is ordered by program order +
// compiler-inserted lgkmcnt (may-alias same array) + the per-brush barrier.

#define E25 1.3887944e-11f   // exp(-25)

__global__ __launch_bounds__(64) void brush_wave(
        const float* __restrict__ brushes,   // [32,64,2]
        const float* __restrict__ patches,   // [32,64,3,16,16]
        float* __restrict__ out)             // [32,3,256,256]
{
    const int b    = blockIdx.z;
    const int tx   = blockIdx.x << 4;
    const int ty   = blockIdx.y << 4;
    const int lane = threadIdx.x;            // 0..63
    const int qi   = lane & 15;              // q / wi / w-col
    const int pi   = lane >> 4;              // 0..3: p mod 4 / h-row group

    __shared__ float4 T4[16 * 21];           // [wi][p(16)+pad5], c-packed

    // zero pads p=16..20 once (stage1 writes only p<16); visible to the
    // first stage2 via the first brush's barrier
    for (int i = lane; i < 80; i += 64)
        T4[(i / 5) * 21 + 16 + (i % 5)] = make_float4(0, 0, 0, 0);

    // wave-private brush table + ballot
    const float2 g0 = ((const float2*)brushes)[(b << 6) + lane];
    const float bx = g0.x * 256.0f, by = g0.y * 256.0f;
    const bool hit =
        (bx >= (float)tx - 9.5f) & (bx <= (float)tx + 24.5f) &
        (by >= (float)ty - 9.5f) & (by <= (float)ty + 24.5f);
    unsigned long long mask = __ballot(hit);

    float acc[4][3];
#pragma unroll
    for (int k = 0; k < 4; ++k) acc[k][0] = acc[k][1] = acc[k][2] = 0.0f;

    while (mask) {
        const int n = __builtin_ctzll(mask);
        mask &= mask - 1;
        const float gx = __shfl(bx, n, 64);  // uniform n -> readlane
        const float gy = __shfl(by, n, 64);

        // patch regs: r[c][k] = patch[c][pi+4k][qi] (12 coalesced b32)
        const float* pb = patches + (size_t)((b << 6) + n) * 768;
        float r[3][4];
#pragma unroll
        for (int c = 0; c < 3; ++c)
#pragma unroll
            for (int k = 0; k < 4; ++k)
                r[c][k] = pb[c * 256 + k * 64 + lane];

        // normalizers, branchless redundant: lane k2=lane&31 -> axis,tap
        float invz;
        {
            const int k2 = lane & 31;
            const float g  = (k2 >> 4) ? gy : gx;
            const float mu = g + (float)(k2 & 15) - 7.5f;
            const float fl = floorf(mu);
            float Z = 0.0f;
#pragma unroll
            for (int d = -1; d <= 2; ++d) {
                const float c = fl + (float)d;
                if (c >= -8.0f && c <= 263.0f) {   // padded coord range
                    const float u = c - mu;
                    Z += __expf(-12.5f * u * u);
                }
            }
            invz = 1.0f / (Z + 1e-7f);
        }
        const float zx = __shfl(invz, qi, 64);          // invZx[qi]
        float zy[4];
#pragma unroll
        for (int k = 0; k < 4; ++k)
            zy[k] = __shfl(invz, 16 + pi + 4 * k, 64);  // invZy[pi+4k]

#pragma unroll
        for (int c = 0; c < 3; ++c)
#pragma unroll
            for (int k = 0; k < 4; ++k)
                r[c][k] *= zx;               // fold invZx at the source

        // ---- stage1: T[wi=qi][p=pi+4k], branchless intra-wave shuffles --
        {
            const float ax  = (float)(tx + qi) - gx + 7.5f;
            const bool  okx = (ax >= -2.5f) & (ax <= 17.5f);
            int qlo = (int)ceilf(ax - 2.0f);
            qlo = qlo < 0 ? 0 : (qlo > 15 ? 15 : qlo);
            float d0 = ax - (float)qlo;
            d0 = fminf(fmaxf(d0, -3.0f), 3.0f);   // keep exp chain finite
            float wgt = okx ? __expf(-12.5f * d0 * d0) : 0.0f;
            float u   = __expf(25.0f * d0 - 12.5f);
            float s0[4] = {0, 0, 0, 0}, s1[4] = {0, 0, 0, 0}, s2[4] = {0, 0, 0, 0};
#pragma unroll
            for (int j = 0; j < 5; ++j) {
                const float wj   = (qlo + j < 16) ? wgt : 0.0f;
                const int   srcl = (pi << 4) + qlo + j;   // in-wave source
#pragma unroll
                for (int k = 0; k < 4; ++k) {             // slot k uniform
                    s0[k] += wj * __shfl(r[0][k], srcl, 64);
                    s1[k] += wj * __shfl(r[1][k], srcl, 64);
                    s2[k] += wj * __shfl(r[2][k], srcl, 64);
                }
                wgt *= u; u *= E25;
            }
#pragma unroll
            for (int k = 0; k < 4; ++k)
                T4[qi * 21 + pi + 4 * k] =
                    make_float4(s0[k] * zy[k], s1[k] * zy[k], s2[k] * zy[k], 0.0f);
        }
        __syncthreads();     // 1-wave block: near-free, orders T4 write->read

        // ---- stage2: 4 pixels/lane, 5 p-taps each from T4 ---------------
#pragma unroll
        for (int k = 0; k < 4; ++k) {
            const float ay = (float)(ty + pi + 4 * k) - gy + 7.5f;
            if (ay < -2.5f || ay > 17.5f) continue;   // divergent ok: LDS only
            int plo = (int)ceilf(ay - 2.0f);
            plo = plo < 0 ? 0 : (plo > 15 ? 15 : plo);
            const float d0 = ay - (float)plo;         // in [-2.5, 2.5]
            float wgt = __expf(-12.5f * d0 * d0);
            float u   = __expf(25.0f * d0 - 12.5f);
            const float4* row = &T4[qi * 21 + plo];
#pragma unroll
            for (int j = 0; j < 5; ++j) {
                const float4 v = row[j];
                acc[k][0] += wgt * v.x; acc[k][1] += wgt * v.y; acc[k][2] += wgt * v.z;
                wgt *= u; u *= E25;
            }
        }
        // next brush's T4 writes are after this wave's reads in program
        // order; compiler orders same-array LDS ops via lgkmcnt
    }

    const float sc = 1.0f / 64.0f;
#pragma unroll
    for (int k = 0; k < 4; ++k) {
        const int h = ty + pi + 4 * k;
        float* ob = out + (((size_t)(b * 3)) << 16) + (h << 8) + tx + qi;
        ob[0]       = acc[k][0] * sc;
        ob[1 << 16] = acc[k][1] * sc;
        ob[2 << 16] = acc[k][2] * sc;
    }
}

extern "C" void kernel_launch(void* const* d_in, const int* in_sizes, int n_in,
                              void* d_out, int out_size, void* d_ws, size_t ws_size,
                              hipStream_t stream) {
    const float* brushes = (const float*)d_in[0];
    const float* patches = (const float*)d_in[1];
    float* out = (float*)d_out;
    brush_wave<<<dim3(16, 16, 32), dim3(64), 0, stream>>>(brushes, patches, out);
}

// Round 12
// 78.821 us; speedup vs baseline: 1.1378x; 1.0372x over previous
//
#include <hip/hip_runtime.h>
#include <hip/hip_bf16.h>

// Separable tile-gather, shuffle-based stage1 (branchless shuffles).
// out[b,c,h,w] = (1/64) Σ_n Σ_p wy[h,p] Σ_q wx[w,q] patch[b,n,c,p,q]
// sigma=0.2 -> support radius 2 px => brush window <=20x20 px.
// One block per 16x16 tile; wave-0 ballot compacts the brush list (~1.13
// survivors/tile). Per brush (2 barriers):
//   B1: invZ ready. stage1: thread (wi=tid&15, p=tid>>4) forms
//       T4[wi][p] = invZy[p] * Σ_j wx_j * (patch[:,p,qlo+j]*invZx[.])
//       via intra-wave __shfl (patch row p lives in the same wave).
//       CRITICAL: shuffles are executed by ALL lanes (uniform control flow) —
//       ds_bpermute reads from exec-masked-off lanes are undefined, so
//       out-of-range lanes must stay active and mask via weights instead.
//   B2: T4 ready. stage2: pixel (w=tid&15, h=tid>>4) takes 5 p-taps from LDS.
// Incremental Gaussian: w_{j+1}=w_j*u, u*=exp(-25); d0 clamped to [-3,3] so
// the chain stays finite for masked lanes (0*finite==0, no NaN).
// T4 pads p=16..20 zeroed once. WAR on T4 (stage2 reads vs next stage1
// writes) is separated by the next iteration's B1.
//
// Session note (R7-R11): this exact structure measured best (78.3 µs wall).
// Falsified alternatives: 32x32 tiles (80.6), prefolded normalizers +
// 1 barrier/brush (81.5), 8-tile strips (89.7), 1 wave/tile (81.8).
// ~57 µs of wall is fixed harness poison/restore; kernel ≈ 21 µs.

#define TILE 16

__global__ __launch_bounds__(256) void brush_tile(
        const float* __restrict__ brushes,   // [32,64,2]
        const float* __restrict__ patches,   // [32,64,3,16,16]
        float* __restrict__ out)             // [32,3,256,256]
{
    const int b   = blockIdx.z;
    const int tx  = blockIdx.x * TILE;
    const int ty  = blockIdx.y * TILE;
    const int tid = threadIdx.x;
    const int qi  = tid & 15;    // q (source) / wi (stage1) / w-col (stage2)
    const int pi  = tid >> 4;    // p (source, stage1) / h-row (stage2)
    const int w   = tx + qi;
    const int h   = ty + pi;

    __shared__ float  gxy[128];              // [n][{gx,gy}] px
    __shared__ unsigned long long smask;
    __shared__ float  invZ[32];              // [0..15]=x, [16..31]=y
    __shared__ float4 T4[16 * 21];           // [wi][p(16)+pad5], c-packed

    // zero T4 pads once (stage1 never writes p>=16)
    if (tid < 80)
        T4[(tid / 5) * 21 + 16 + (tid % 5)] = make_float4(0, 0, 0, 0);

    // wave 0: load + scale coords, ballot vs tile window, stage to LDS
    if (tid < 64) {
        float2 g = ((const float2*)brushes)[(b << 6) + tid];
        g.x *= 256.0f; g.y *= 256.0f;
        ((float2*)gxy)[tid] = g;
        const bool hit =
            (g.x >= (float)tx - 9.5f) & (g.x <= (float)tx + 24.5f) &
            (g.y >= (float)ty - 9.5f) & (g.y <= (float)ty + 24.5f);
        const unsigned long long m = __ballot(hit);
        if (tid == 0) smask = m;
    }
    __syncthreads();                                     // B0
    unsigned long long mask = smask;

    float acc0 = 0.0f, acc1 = 0.0f, acc2 = 0.0f;
    const float E25 = 1.3887944e-11f;                    // exp(-25)

    while (mask) {
        const int n = __builtin_ctzll(mask);
        mask &= mask - 1;
        const float gx = gxy[2 * n], gy = gxy[2 * n + 1];

        // patch loads: 3 coalesced b32, in flight across invZ + B1
        const float* pb = patches + (size_t)((b << 6) + n) * 768;
        const float r0 = pb[tid];
        const float r1 = pb[tid + 256];
        const float r2 = pb[tid + 512];

        if (tid < 32) {                      // normalizers
            const int axis = tid >> 4, q = tid & 15;
            const float g  = axis ? gy : gx;
            const float mu = g + (float)q - 7.5f;
            const float fl = floorf(mu);
            float Z = 0.0f;
#pragma unroll
            for (int d = -1; d <= 2; ++d) {
                const float c = fl + (float)d;
                if (c >= -8.0f && c <= 263.0f) {   // padded coord range
                    const float u = c - mu;
                    Z += __expf(-12.5f * u * u);
                }
            }
            invZ[tid] = 1.0f / (Z + 1e-7f);
        }
        __syncthreads();                                 // B1

        // pre-scale own patch element by invZx[its q]
        const float zx = invZ[qi];
        const float v0 = r0 * zx, v1 = r1 * zx, v2 = r2 * zx;

        // stage1: T4[wi=qi][p=pi] via intra-wave shuffles — BRANCHLESS
        {
            const float ax  = (float)w - gx + 7.5f;
            const bool  okx = (ax >= -2.5f) & (ax <= 17.5f);
            int qlo = (int)ceilf(ax - 2.0f);
            qlo = qlo < 0 ? 0 : (qlo > 15 ? 15 : qlo);
            float d0 = ax - (float)qlo;
            d0 = fminf(fmaxf(d0, -3.0f), 3.0f);          // keep exp chain finite
            float wgt = okx ? __expf(-12.5f * d0 * d0) : 0.0f;
            float u   = __expf(25.0f * d0 - 12.5f);      // <= e^62.5, finite
            const int base = ((pi & 3) << 4) + qlo;      // intra-wave src lane
            float4 s = make_float4(0, 0, 0, 0);
#pragma unroll
            for (int j = 0; j < 5; ++j) {
                const float a0 = __shfl(v0, base + j, 64);  // all lanes active
                const float a1 = __shfl(v1, base + j, 64);
                const float a2 = __shfl(v2, base + j, 64);
                const float wj = (qlo + j < 16) ? wgt : 0.0f;
                s.x += wj * a0; s.y += wj * a1; s.z += wj * a2;
                wgt *= u; u *= E25;
            }
            const float zy = invZ[16 + pi];
            s.x *= zy; s.y *= zy; s.z *= zy;
            T4[qi * 21 + pi] = s;
        }
        __syncthreads();                                 // B2

        // stage2: 5 p-taps from T4 row (pads are exact zeros; LDS reads
        // don't depend on other lanes' exec mask, so divergence is fine)
        {
            const float ay = (float)h - gy + 7.5f;
            if (ay >= -2.5f && ay <= 17.5f) {
                int plo = (int)ceilf(ay - 2.0f);
                plo = plo < 0 ? 0 : (plo > 15 ? 15 : plo);
                const float d0 = ay - (float)plo;        // in [-2.5, 2.5]
                float wgt = __expf(-12.5f * d0 * d0);
                float u   = __expf(25.0f * d0 - 12.5f);
                const float4* row = &T4[qi * 21 + plo];
#pragma unroll
                for (int j = 0; j < 5; ++j) {
                    const float4 v = row[j];
                    acc0 += wgt * v.x; acc1 += wgt * v.y; acc2 += wgt * v.z;
                    wgt *= u; u *= E25;
                }
            }
        }
        // next iteration's B1 separates these T4 reads from the next writes
    }

    const float sc = 1.0f / 64.0f;
    float* ob = out + (((size_t)(b * 3)) << 16) + (h << 8) + w;
    ob[0]       = acc0 * sc;
    ob[1 << 16] = acc1 * sc;
    ob[2 << 16] = acc2 * sc;
}

extern "C" void kernel_launch(void* const* d_in, const int* in_sizes, int n_in,
                              void* d_out, int out_size, void* d_ws, size_t ws_size,
                              hipStream_t stream) {
    const float* brushes = (const float*)d_in[0];
    const float* patches = (const float*)d_in[1];
    float* out = (float*)d_out;
    brush_tile<<<dim3(16, 16, 32), dim3(256), 0, stream>>>(brushes, patches, out);
}